// Round 1
// baseline (2487.910 us; speedup 1.0000x reference)
//
#include <hip/hip_runtime.h>

#define CDIM 128
#define EPS 1e-5f

// ---------------- degree / dinv ----------------
__global__ __launch_bounds__(256) void deg_kernel(const int* __restrict__ dst,
                                                  float* __restrict__ deg, int E) {
    int e = blockIdx.x * 256 + threadIdx.x;
    if (e < E) atomicAdd(&deg[dst[e]], 1.0f);
}

__global__ __launch_bounds__(256) void dinv_kernel(const float* __restrict__ deg,
                                                   float* __restrict__ dinv, int N) {
    int i = blockIdx.x * 256 + threadIdx.x;
    if (i < N) dinv[i] = rsqrtf(deg[i] + 1.0f);  // +1 self-loop
}

// ---------------- per-feature stats (sum, sumsq) over node dim ----------------
__global__ __launch_bounds__(256) void stats_kernel(const float* __restrict__ v, int N,
                                                    float* __restrict__ sum,
                                                    float* __restrict__ sq) {
    __shared__ float s_sum[CDIM];
    __shared__ float s_sq[CDIM];
    int t = threadIdx.x;
    if (t < CDIM) { s_sum[t] = 0.f; s_sq[t] = 0.f; }
    __syncthreads();
    int cg = t & 31, rg = t >> 5;
    int c0 = cg * 4;
    float a0=0,a1=0,a2=0,a3=0,q0=0,q1=0,q2=0,q3=0;
    for (long row = (long)blockIdx.x * 8 + rg; row < N; row += (long)gridDim.x * 8) {
        float4 x4 = *(const float4*)(v + row * CDIM + c0);
        a0 += x4.x; q0 = fmaf(x4.x, x4.x, q0);
        a1 += x4.y; q1 = fmaf(x4.y, x4.y, q1);
        a2 += x4.z; q2 = fmaf(x4.z, x4.z, q2);
        a3 += x4.w; q3 = fmaf(x4.w, x4.w, q3);
    }
    atomicAdd(&s_sum[c0+0], a0); atomicAdd(&s_sum[c0+1], a1);
    atomicAdd(&s_sum[c0+2], a2); atomicAdd(&s_sum[c0+3], a3);
    atomicAdd(&s_sq[c0+0], q0);  atomicAdd(&s_sq[c0+1], q1);
    atomicAdd(&s_sq[c0+2], q2);  atomicAdd(&s_sq[c0+3], q3);
    __syncthreads();
    if (t < CDIM) { atomicAdd(&sum[t], s_sum[t]); atomicAdd(&sq[t], s_sq[t]); }
}

// ---------------- BN params: scale = gamma*rsqrt(var+eps), bias = beta - mu*scale ----
__global__ void prep_kernel(const float* __restrict__ sum, const float* __restrict__ sq,
                            const float* __restrict__ gamma, const float* __restrict__ beta,
                            float* __restrict__ scale, float* __restrict__ bias, float inv_n) {
    int c = threadIdx.x;
    float m = sum[c] * inv_n;
    float var = fmaf(-m, m, sq[c] * inv_n);
    float r = rsqrtf(var + EPS);
    float g = gamma[c] * r;
    scale[c] = g;
    bias[c] = fmaf(-m, g, beta[c]);
}

// ---------------- GEMM: Y = (scale*X+bias) @ W, X:[N,128], W:[128,128] ----------------
__global__ __launch_bounds__(256) void gemm_kernel(const float* __restrict__ X,
                                                   const float* __restrict__ W,
                                                   const float* __restrict__ scale,
                                                   const float* __restrict__ bias,
                                                   float* __restrict__ Y, int N) {
    __shared__ float xs[32 * CDIM];
    int t = threadIdx.x;
    long row0 = (long)blockIdx.x * 32;
    #pragma unroll
    for (int p = 0; p < 4; ++p) {
        int idx = p * 1024 + t * 4;
        long r = row0 + (idx >> 7);
        int c = idx & 127;
        float4 v;
        if (r < N) v = *(const float4*)(X + r * CDIM + c);
        else       v = make_float4(0.f, 0.f, 0.f, 0.f);
        float4 sc = *(const float4*)(scale + c);
        float4 bi = *(const float4*)(bias + c);
        v.x = fmaf(v.x, sc.x, bi.x);
        v.y = fmaf(v.y, sc.y, bi.y);
        v.z = fmaf(v.z, sc.z, bi.z);
        v.w = fmaf(v.w, sc.w, bi.w);
        *(float4*)&xs[idx] = v;
    }
    __syncthreads();
    int tx = t & 127, ty = t >> 7;
    float acc[16];
    #pragma unroll
    for (int i = 0; i < 16; ++i) acc[i] = 0.f;
    for (int k = 0; k < CDIM; k += 4) {
        float w0 = W[(k+0) * CDIM + tx];
        float w1 = W[(k+1) * CDIM + tx];
        float w2 = W[(k+2) * CDIM + tx];
        float w3 = W[(k+3) * CDIM + tx];
        #pragma unroll
        for (int i = 0; i < 16; ++i) {
            const float4 xv = *(const float4*)&xs[(ty * 16 + i) * CDIM + k];
            acc[i] = fmaf(xv.x, w0, acc[i]);
            acc[i] = fmaf(xv.y, w1, acc[i]);
            acc[i] = fmaf(xv.z, w2, acc[i]);
            acc[i] = fmaf(xv.w, w3, acc[i]);
        }
    }
    #pragma unroll
    for (int i = 0; i < 16; ++i) {
        long r = row0 + ty * 16 + i;
        if (r < N) Y[r * CDIM + tx] = acc[i];
    }
}

// ---------------- edge aggregation: agg[dst] += h[src] * dinv[src]*dinv[dst] ----------
__global__ __launch_bounds__(256) void agg_kernel(const float* __restrict__ h,
                                                  const int* __restrict__ src,
                                                  const int* __restrict__ dst,
                                                  const float* __restrict__ dinv,
                                                  float* __restrict__ agg, int E) {
    long g = (long)blockIdx.x * 256 + threadIdx.x;
    long e = g >> 5;
    if (e >= E) return;
    int lane4 = (int)(g & 31);
    int s = src[e], d = dst[e];
    float w = dinv[s] * dinv[d];
    const float4 v = *(const float4*)(h + (long)s * CDIM + lane4 * 4);
    float* o = agg + (long)d * CDIM + lane4 * 4;
    atomicAdd(o + 0, v.x * w);
    atomicAdd(o + 1, v.y * w);
    atomicAdd(o + 2, v.z * w);
    atomicAdd(o + 3, v.w * w);
}

// ---------------- post: v = relu(agg + h*dinv^2 + b), in-place into agg, + stats ------
__global__ __launch_bounds__(256) void post_kernel(float* __restrict__ agg,
                                                   const float* __restrict__ h,
                                                   const float* __restrict__ bvec,
                                                   const float* __restrict__ dinv, int N,
                                                   float* __restrict__ sum,
                                                   float* __restrict__ sq) {
    __shared__ float s_sum[CDIM];
    __shared__ float s_sq[CDIM];
    int t = threadIdx.x;
    if (t < CDIM) { s_sum[t] = 0.f; s_sq[t] = 0.f; }
    __syncthreads();
    int cg = t & 31, rg = t >> 5;
    int c0 = cg * 4;
    float4 bb = *(const float4*)(bvec + c0);
    float a0=0,a1=0,a2=0,a3=0,q0=0,q1=0,q2=0,q3=0;
    for (long row = (long)blockIdx.x * 8 + rg; row < N; row += (long)gridDim.x * 8) {
        float di = dinv[row];
        float d2 = di * di;
        float4 g4 = *(const float4*)(agg + row * CDIM + c0);
        float4 h4 = *(const float4*)(h + row * CDIM + c0);
        float v0 = fmaxf(fmaf(h4.x, d2, g4.x) + bb.x, 0.f);
        float v1 = fmaxf(fmaf(h4.y, d2, g4.y) + bb.y, 0.f);
        float v2 = fmaxf(fmaf(h4.z, d2, g4.z) + bb.z, 0.f);
        float v3 = fmaxf(fmaf(h4.w, d2, g4.w) + bb.w, 0.f);
        a0 += v0; q0 = fmaf(v0, v0, q0);
        a1 += v1; q1 = fmaf(v1, v1, q1);
        a2 += v2; q2 = fmaf(v2, v2, q2);
        a3 += v3; q3 = fmaf(v3, v3, q3);
        float4 o = make_float4(v0, v1, v2, v3);
        *(float4*)(agg + row * CDIM + c0) = o;
    }
    atomicAdd(&s_sum[c0+0], a0); atomicAdd(&s_sum[c0+1], a1);
    atomicAdd(&s_sum[c0+2], a2); atomicAdd(&s_sum[c0+3], a3);
    atomicAdd(&s_sq[c0+0], q0);  atomicAdd(&s_sq[c0+1], q1);
    atomicAdd(&s_sq[c0+2], q2);  atomicAdd(&s_sq[c0+3], q3);
    __syncthreads();
    if (t < CDIM) { atomicAdd(&sum[t], s_sum[t]); atomicAdd(&sq[t], s_sq[t]); }
}

// ---------------- final: out = bn0(x) + bn2(v2) ----------------
__global__ __launch_bounds__(256) void final_kernel(const float* __restrict__ x,
                                                    const float* __restrict__ v,
                                                    const float* __restrict__ sc0,
                                                    const float* __restrict__ bi0,
                                                    const float* __restrict__ sc2,
                                                    const float* __restrict__ bi2,
                                                    float* __restrict__ out, int N) {
    int t = threadIdx.x;
    int cg = t & 31, rg = t >> 5;
    int c0 = cg * 4;
    float4 s0 = *(const float4*)(sc0 + c0);
    float4 b0 = *(const float4*)(bi0 + c0);
    float4 s2 = *(const float4*)(sc2 + c0);
    float4 b2 = *(const float4*)(bi2 + c0);
    for (long row = (long)blockIdx.x * 8 + rg; row < N; row += (long)gridDim.x * 8) {
        float4 xv = *(const float4*)(x + row * CDIM + c0);
        float4 vv = *(const float4*)(v + row * CDIM + c0);
        float4 o;
        o.x = fmaf(xv.x, s0.x, b0.x) + fmaf(vv.x, s2.x, b2.x);
        o.y = fmaf(xv.y, s0.y, b0.y) + fmaf(vv.y, s2.y, b2.y);
        o.z = fmaf(xv.z, s0.z, b0.z) + fmaf(vv.z, s2.z, b2.z);
        o.w = fmaf(xv.w, s0.w, b0.w) + fmaf(vv.w, s2.w, b2.w);
        *(float4*)(out + row * CDIM + c0) = o;
    }
}

extern "C" void kernel_launch(void* const* d_in, const int* in_sizes, int n_in,
                              void* d_out, int out_size, void* d_ws, size_t ws_size,
                              hipStream_t stream) {
    const float* x   = (const float*)d_in[0];
    const int*   ei  = (const int*)d_in[1];
    const float* g0  = (const float*)d_in[2];
    const float* be0 = (const float*)d_in[3];
    const float* W1  = (const float*)d_in[4];
    const float* b1  = (const float*)d_in[5];
    const float* g1  = (const float*)d_in[6];
    const float* be1 = (const float*)d_in[7];
    const float* W2  = (const float*)d_in[8];
    const float* b2  = (const float*)d_in[9];
    const float* g2  = (const float*)d_in[10];
    const float* be2 = (const float*)d_in[11];
    float* out = (float*)d_out;

    int N = in_sizes[0] / CDIM;
    int E = in_sizes[1] / 2;
    const int* src = ei;
    const int* dst = ei + E;

    size_t NC = (size_t)N * CDIM;
    float* B    = (float*)d_ws;
    float* Cb   = B + NC;
    float* deg  = Cb + NC;
    float* dinv = deg + N;
    float* stat = dinv + N;          // 6*128 floats
    float* sb   = stat + 6 * CDIM;   // 6*128 floats
    float* sum0 = stat;              float* sq0 = stat + 128;
    float* sum1 = stat + 256;        float* sq1 = stat + 384;
    float* sum2 = stat + 512;        float* sq2 = stat + 640;
    float* sc0 = sb;                 float* bi0 = sb + 128;
    float* sc1 = sb + 256;           float* bi1 = sb + 384;
    float* sc2 = sb + 512;           float* bi2 = sb + 640;

    float inv_n = 1.0f / (float)N;

    // zero deg + dinv + stats region
    hipMemsetAsync(deg, 0, (2 * (size_t)N + 6 * CDIM) * sizeof(float), stream);

    // degree + dinv
    deg_kernel<<<(E + 255) / 256, 256, 0, stream>>>(dst, deg, E);
    dinv_kernel<<<(N + 255) / 256, 256, 0, stream>>>(deg, dinv, N);

    // bn0 stats from x, then params
    stats_kernel<<<1024, 256, 0, stream>>>(x, N, sum0, sq0);
    prep_kernel<<<1, 128, 0, stream>>>(sum0, sq0, g0, be0, sc0, bi0, inv_n);

    // layer 1: h1 = bn0(x) @ W1  -> B
    gemm_kernel<<<(N + 31) / 32, 256, 0, stream>>>(x, W1, sc0, bi0, B, N);
    hipMemsetAsync(Cb, 0, NC * sizeof(float), stream);
    agg_kernel<<<(int)(((long)E * 32 + 255) / 256), 256, 0, stream>>>(B, src, dst, dinv, Cb, E);
    post_kernel<<<1024, 256, 0, stream>>>(Cb, B, b1, dinv, N, sum1, sq1);
    prep_kernel<<<1, 128, 0, stream>>>(sum1, sq1, g1, be1, sc1, bi1, inv_n);

    // layer 2: h2 = bn1(v1) @ W2  -> B  (reads Cb with bn1 fused)
    gemm_kernel<<<(N + 31) / 32, 256, 0, stream>>>(Cb, W2, sc1, bi1, B, N);
    hipMemsetAsync(Cb, 0, NC * sizeof(float), stream);
    agg_kernel<<<(int)(((long)E * 32 + 255) / 256), 256, 0, stream>>>(B, src, dst, dinv, Cb, E);
    post_kernel<<<1024, 256, 0, stream>>>(Cb, B, b2, dinv, N, sum2, sq2);
    prep_kernel<<<1, 128, 0, stream>>>(sum2, sq2, g2, be2, sc2, bi2, inv_n);

    // out = bn0(x) + bn2(v2)
    final_kernel<<<1024, 256, 0, stream>>>(x, Cb, sc0, bi0, sc2, bi2, out, N);
}

// Round 2
// 586.472 us; speedup vs baseline: 4.2422x; 4.2422x over previous
//
#include <hip/hip_runtime.h>

#define CDIM 128
#define EPS 1e-5f

// ---------------- int degree histogram ----------------
__global__ __launch_bounds__(256) void hist_kernel(const int* __restrict__ dst,
                                                   int* __restrict__ deg, int E) {
    int e = blockIdx.x * 256 + threadIdx.x;
    if (e < E) atomicAdd(&deg[dst[e]], 1);
}

__global__ __launch_bounds__(256) void dinv_kernel(const int* __restrict__ deg,
                                                   float* __restrict__ dinv, int N) {
    int i = blockIdx.x * 256 + threadIdx.x;
    if (i < N) dinv[i] = rsqrtf((float)deg[i] + 1.0f);  // +1 self-loop
}

// ---------------- scan stage 1: per-1024-chunk sums ----------------
__global__ __launch_bounds__(256) void scan1_kernel(const int* __restrict__ deg,
                                                    int* __restrict__ part, int N) {
    int t = threadIdx.x;
    int base = blockIdx.x * 1024 + t * 4;
    int s = 0;
    if (base + 3 < N) {
        int4 v = *(const int4*)(deg + base);
        s = v.x + v.y + v.z + v.w;
    } else {
        for (int k = 0; k < 4; ++k) { int i = base + k; if (i < N) s += deg[i]; }
    }
    for (int off = 32; off; off >>= 1) s += __shfl_down(s, off, 64);
    __shared__ int sh[4];
    if ((t & 63) == 0) sh[t >> 6] = s;
    __syncthreads();
    if (t == 0) part[blockIdx.x] = sh[0] + sh[1] + sh[2] + sh[3];
}

// ---------------- scan stage 2: exclusive scan of <=256 partials ----------------
__global__ __launch_bounds__(256) void scan2_kernel(int* __restrict__ part, int P) {
    int t = threadIdx.x;
    __shared__ int sh[256];
    int v = (t < P) ? part[t] : 0;
    sh[t] = v;
    __syncthreads();
    for (int off = 1; off < 256; off <<= 1) {
        int u = (t >= off) ? sh[t - off] : 0;
        __syncthreads();
        sh[t] += u;
        __syncthreads();
    }
    if (t < P) part[t] = sh[t] - v;  // exclusive
}

// ---------------- scan stage 3: rowstart + cursor ----------------
__global__ __launch_bounds__(256) void scan3_kernel(const int* __restrict__ deg,
                                                    const int* __restrict__ part,
                                                    int* __restrict__ rowst,
                                                    int* __restrict__ cursor, int N) {
    int t = threadIdx.x, b = blockIdx.x;
    int base = b * 1024 + t * 4;
    int d0 = 0, d1 = 0, d2 = 0, d3 = 0;
    if (base + 3 < N) {
        int4 v = *(const int4*)(deg + base);
        d0 = v.x; d1 = v.y; d2 = v.z; d3 = v.w;
    } else {
        if (base < N)     d0 = deg[base];
        if (base + 1 < N) d1 = deg[base + 1];
        if (base + 2 < N) d2 = deg[base + 2];
        if (base + 3 < N) d3 = deg[base + 3];
    }
    int c0 = d0, c1 = c0 + d1, c2 = c1 + d2, c3 = c2 + d3;
    __shared__ int sh[256];
    sh[t] = c3;
    __syncthreads();
    for (int off = 1; off < 256; off <<= 1) {
        int u = (t >= off) ? sh[t - off] : 0;
        __syncthreads();
        sh[t] += u;
        __syncthreads();
    }
    int basev = part[b] + sh[t] - c3;
    int r0 = basev, r1 = basev + c0, r2 = basev + c1, r3 = basev + c2;
    if (base < N)     { rowst[base] = r0;     cursor[base] = r0;     if (base == N - 1)     rowst[N] = r0 + d0; }
    if (base + 1 < N) { rowst[base + 1] = r1; cursor[base + 1] = r1; if (base + 1 == N - 1) rowst[N] = r1 + d1; }
    if (base + 2 < N) { rowst[base + 2] = r2; cursor[base + 2] = r2; if (base + 2 == N - 1) rowst[N] = r2 + d2; }
    if (base + 3 < N) { rowst[base + 3] = r3; cursor[base + 3] = r3; if (base + 3 == N - 1) rowst[N] = r3 + d3; }
}

// ---------------- scatter src into CSR ----------------
__global__ __launch_bounds__(256) void scatter_kernel(const int* __restrict__ src,
                                                      const int* __restrict__ dst,
                                                      int* __restrict__ cursor,
                                                      int* __restrict__ csr, int E) {
    int e = blockIdx.x * 256 + threadIdx.x;
    if (e < E) {
        int d = dst[e];
        int pos = atomicAdd(&cursor[d], 1);
        csr[pos] = src[e];
    }
}

// ---------------- per-feature stats over node dim ----------------
__global__ __launch_bounds__(256) void stats_kernel(const float* __restrict__ v, int N,
                                                    float* __restrict__ sum,
                                                    float* __restrict__ sq) {
    __shared__ float s_sum[CDIM];
    __shared__ float s_sq[CDIM];
    int t = threadIdx.x;
    if (t < CDIM) { s_sum[t] = 0.f; s_sq[t] = 0.f; }
    __syncthreads();
    int cg = t & 31, rg = t >> 5;
    int c0 = cg * 4;
    float a0=0,a1=0,a2=0,a3=0,q0=0,q1=0,q2=0,q3=0;
    for (long row = (long)blockIdx.x * 8 + rg; row < N; row += (long)gridDim.x * 8) {
        float4 x4 = *(const float4*)(v + row * CDIM + c0);
        a0 += x4.x; q0 = fmaf(x4.x, x4.x, q0);
        a1 += x4.y; q1 = fmaf(x4.y, x4.y, q1);
        a2 += x4.z; q2 = fmaf(x4.z, x4.z, q2);
        a3 += x4.w; q3 = fmaf(x4.w, x4.w, q3);
    }
    atomicAdd(&s_sum[c0+0], a0); atomicAdd(&s_sum[c0+1], a1);
    atomicAdd(&s_sum[c0+2], a2); atomicAdd(&s_sum[c0+3], a3);
    atomicAdd(&s_sq[c0+0], q0);  atomicAdd(&s_sq[c0+1], q1);
    atomicAdd(&s_sq[c0+2], q2);  atomicAdd(&s_sq[c0+3], q3);
    __syncthreads();
    if (t < CDIM) { atomicAdd(&sum[t], s_sum[t]); atomicAdd(&sq[t], s_sq[t]); }
}

// ---------------- BN params ----------------
__global__ void prep_kernel(const float* __restrict__ sum, const float* __restrict__ sq,
                            const float* __restrict__ gamma, const float* __restrict__ beta,
                            float* __restrict__ scale, float* __restrict__ bias, float inv_n) {
    int c = threadIdx.x;
    float m = sum[c] * inv_n;
    float var = fmaf(-m, m, sq[c] * inv_n);
    float r = rsqrtf(var + EPS);
    float g = gamma[c] * r;
    scale[c] = g;
    bias[c] = fmaf(-m, g, beta[c]);
}

// ---------------- GEMM: Y = (scale*X+bias) @ W ----------------
__global__ __launch_bounds__(256) void gemm_kernel(const float* __restrict__ X,
                                                   const float* __restrict__ W,
                                                   const float* __restrict__ scale,
                                                   const float* __restrict__ bias,
                                                   float* __restrict__ Y, int N) {
    __shared__ float xs[32 * CDIM];
    int t = threadIdx.x;
    long row0 = (long)blockIdx.x * 32;
    #pragma unroll
    for (int p = 0; p < 4; ++p) {
        int idx = p * 1024 + t * 4;
        long r = row0 + (idx >> 7);
        int c = idx & 127;
        float4 v;
        if (r < N) v = *(const float4*)(X + r * CDIM + c);
        else       v = make_float4(0.f, 0.f, 0.f, 0.f);
        float4 sc = *(const float4*)(scale + c);
        float4 bi = *(const float4*)(bias + c);
        v.x = fmaf(v.x, sc.x, bi.x);
        v.y = fmaf(v.y, sc.y, bi.y);
        v.z = fmaf(v.z, sc.z, bi.z);
        v.w = fmaf(v.w, sc.w, bi.w);
        *(float4*)&xs[idx] = v;
    }
    __syncthreads();
    int tx = t & 127, ty = t >> 7;
    float acc[16];
    #pragma unroll
    for (int i = 0; i < 16; ++i) acc[i] = 0.f;
    for (int k = 0; k < CDIM; k += 4) {
        float w0 = W[(k+0) * CDIM + tx];
        float w1 = W[(k+1) * CDIM + tx];
        float w2 = W[(k+2) * CDIM + tx];
        float w3 = W[(k+3) * CDIM + tx];
        #pragma unroll
        for (int i = 0; i < 16; ++i) {
            const float4 xv = *(const float4*)&xs[(ty * 16 + i) * CDIM + k];
            acc[i] = fmaf(xv.x, w0, acc[i]);
            acc[i] = fmaf(xv.y, w1, acc[i]);
            acc[i] = fmaf(xv.z, w2, acc[i]);
            acc[i] = fmaf(xv.w, w3, acc[i]);
        }
    }
    #pragma unroll
    for (int i = 0; i < 16; ++i) {
        long r = row0 + ty * 16 + i;
        if (r < N) Y[r * CDIM + tx] = acc[i];
    }
}

// ------ fused gather-agg + self-loop + bias + relu + BN stats ------
__global__ __launch_bounds__(256) void gather_kernel(const float* __restrict__ h,
                                                     const int* __restrict__ rowst,
                                                     const int* __restrict__ csr,
                                                     const float* __restrict__ dinv,
                                                     const float* __restrict__ bvec,
                                                     float* __restrict__ vout, int N,
                                                     float* __restrict__ sum,
                                                     float* __restrict__ sq) {
    __shared__ float s_sum[CDIM];
    __shared__ float s_sq[CDIM];
    int t = threadIdx.x;
    if (t < CDIM) { s_sum[t] = 0.f; s_sq[t] = 0.f; }
    __syncthreads();
    int grp = t >> 5, lane = t & 31;
    int c0 = lane * 4;
    float4 bb = *(const float4*)(bvec + c0);
    float a0=0,a1=0,a2=0,a3=0,q0=0,q1=0,q2=0,q3=0;
    for (int n = blockIdx.x * 8 + grp; n < N; n += gridDim.x * 8) {
        int r0 = rowst[n], r1 = rowst[n + 1];
        float dn = dinv[n];
        float d2 = dn * dn;
        float4 hn = *(const float4*)(h + (long)n * CDIM + c0);
        float x0 = hn.x * d2, x1 = hn.y * d2, x2 = hn.z * d2, x3 = hn.w * d2;
        int j = r0;
        for (; j + 2 <= r1; j += 2) {
            int s0 = csr[j], s1 = csr[j + 1];
            float w0 = dinv[s0] * dn, w1 = dinv[s1] * dn;
            float4 v0 = *(const float4*)(h + (long)s0 * CDIM + c0);
            float4 v1 = *(const float4*)(h + (long)s1 * CDIM + c0);
            x0 = fmaf(v0.x, w0, x0); x1 = fmaf(v0.y, w0, x1);
            x2 = fmaf(v0.z, w0, x2); x3 = fmaf(v0.w, w0, x3);
            x0 = fmaf(v1.x, w1, x0); x1 = fmaf(v1.y, w1, x1);
            x2 = fmaf(v1.z, w1, x2); x3 = fmaf(v1.w, w1, x3);
        }
        if (j < r1) {
            int s0 = csr[j];
            float w0 = dinv[s0] * dn;
            float4 v0 = *(const float4*)(h + (long)s0 * CDIM + c0);
            x0 = fmaf(v0.x, w0, x0); x1 = fmaf(v0.y, w0, x1);
            x2 = fmaf(v0.z, w0, x2); x3 = fmaf(v0.w, w0, x3);
        }
        float o0 = fmaxf(x0 + bb.x, 0.f);
        float o1 = fmaxf(x1 + bb.y, 0.f);
        float o2 = fmaxf(x2 + bb.z, 0.f);
        float o3 = fmaxf(x3 + bb.w, 0.f);
        *(float4*)(vout + (long)n * CDIM + c0) = make_float4(o0, o1, o2, o3);
        a0 += o0; q0 = fmaf(o0, o0, q0);
        a1 += o1; q1 = fmaf(o1, o1, q1);
        a2 += o2; q2 = fmaf(o2, o2, q2);
        a3 += o3; q3 = fmaf(o3, o3, q3);
    }
    atomicAdd(&s_sum[c0+0], a0); atomicAdd(&s_sum[c0+1], a1);
    atomicAdd(&s_sum[c0+2], a2); atomicAdd(&s_sum[c0+3], a3);
    atomicAdd(&s_sq[c0+0], q0);  atomicAdd(&s_sq[c0+1], q1);
    atomicAdd(&s_sq[c0+2], q2);  atomicAdd(&s_sq[c0+3], q3);
    __syncthreads();
    if (t < CDIM) { atomicAdd(&sum[t], s_sum[t]); atomicAdd(&sq[t], s_sq[t]); }
}

// ---------------- final: out = bn0(x) + bn2(v2) ----------------
__global__ __launch_bounds__(256) void final_kernel(const float* __restrict__ x,
                                                    const float* __restrict__ v,
                                                    const float* __restrict__ sc0,
                                                    const float* __restrict__ bi0,
                                                    const float* __restrict__ sc2,
                                                    const float* __restrict__ bi2,
                                                    float* __restrict__ out, int N) {
    int t = threadIdx.x;
    int cg = t & 31, rg = t >> 5;
    int c0 = cg * 4;
    float4 s0 = *(const float4*)(sc0 + c0);
    float4 b0 = *(const float4*)(bi0 + c0);
    float4 s2 = *(const float4*)(sc2 + c0);
    float4 b2 = *(const float4*)(bi2 + c0);
    for (long row = (long)blockIdx.x * 8 + rg; row < N; row += (long)gridDim.x * 8) {
        float4 xv = *(const float4*)(x + row * CDIM + c0);
        float4 vv = *(const float4*)(v + row * CDIM + c0);
        float4 o;
        o.x = fmaf(xv.x, s0.x, b0.x) + fmaf(vv.x, s2.x, b2.x);
        o.y = fmaf(xv.y, s0.y, b0.y) + fmaf(vv.y, s2.y, b2.y);
        o.z = fmaf(xv.z, s0.z, b0.z) + fmaf(vv.z, s2.z, b2.z);
        o.w = fmaf(xv.w, s0.w, b0.w) + fmaf(vv.w, s2.w, b2.w);
        *(float4*)(out + row * CDIM + c0) = o;
    }
}

extern "C" void kernel_launch(void* const* d_in, const int* in_sizes, int n_in,
                              void* d_out, int out_size, void* d_ws, size_t ws_size,
                              hipStream_t stream) {
    const float* x   = (const float*)d_in[0];
    const int*   ei  = (const int*)d_in[1];
    const float* g0  = (const float*)d_in[2];
    const float* be0 = (const float*)d_in[3];
    const float* W1  = (const float*)d_in[4];
    const float* b1  = (const float*)d_in[5];
    const float* g1  = (const float*)d_in[6];
    const float* be1 = (const float*)d_in[7];
    const float* W2  = (const float*)d_in[8];
    const float* b2  = (const float*)d_in[9];
    const float* g2  = (const float*)d_in[10];
    const float* be2 = (const float*)d_in[11];
    float* out = (float*)d_out;

    int N = in_sizes[0] / CDIM;
    int E = in_sizes[1] / 2;
    const int* src = ei;
    const int* dst = ei + E;

    size_t NC = (size_t)N * CDIM;
    float* B    = (float*)d_ws;          // [N,128] h buffer
    float* Cb   = B + NC;                // [N,128] v buffer
    float* dinv = Cb + NC;               // N
    float* stat = dinv + N;              // 768 floats (zeroed)
    int*   deg  = (int*)(stat + 768);    // N ints (zeroed, contiguous with stat)
    int*   rowst= deg + N;               // N+1
    int*   cursor = rowst + N + 1;       // N
    int*   csr  = cursor + N;            // E
    int*   part = csr + E;               // <=256
    float* sb   = (float*)(part + 256);  // 768 floats

    float* sum0 = stat;       float* sq0 = stat + 128;
    float* sum1 = stat + 256; float* sq1 = stat + 384;
    float* sum2 = stat + 512; float* sq2 = stat + 640;
    float* sc0 = sb;          float* bi0 = sb + 128;
    float* sc1 = sb + 256;    float* bi1 = sb + 384;
    float* sc2 = sb + 512;    float* bi2 = sb + 640;

    float inv_n = 1.0f / (float)N;
    int P = (N + 1023) / 1024;  // scan chunks (<=256 for N<=262144)

    // zero stats + degree (contiguous region)
    hipMemsetAsync(stat, 0, (768 + (size_t)N) * sizeof(float), stream);

    // ---- CSR build (shared by both layers) ----
    hist_kernel<<<(E + 255) / 256, 256, 0, stream>>>(dst, deg, E);
    scan1_kernel<<<P, 256, 0, stream>>>(deg, part, N);
    scan2_kernel<<<1, 256, 0, stream>>>(part, P);
    scan3_kernel<<<P, 256, 0, stream>>>(deg, part, rowst, cursor, N);
    dinv_kernel<<<(N + 255) / 256, 256, 0, stream>>>(deg, dinv, N);
    scatter_kernel<<<(E + 255) / 256, 256, 0, stream>>>(src, dst, cursor, csr, E);

    // ---- bn0 stats ----
    stats_kernel<<<1024, 256, 0, stream>>>(x, N, sum0, sq0);
    prep_kernel<<<1, 128, 0, stream>>>(sum0, sq0, g0, be0, sc0, bi0, inv_n);

    // ---- layer 1 ----
    gemm_kernel<<<(N + 31) / 32, 256, 0, stream>>>(x, W1, sc0, bi0, B, N);
    gather_kernel<<<2048, 256, 0, stream>>>(B, rowst, csr, dinv, b1, Cb, N, sum1, sq1);
    prep_kernel<<<1, 128, 0, stream>>>(sum1, sq1, g1, be1, sc1, bi1, inv_n);

    // ---- layer 2 ----
    gemm_kernel<<<(N + 31) / 32, 256, 0, stream>>>(Cb, W2, sc1, bi1, B, N);
    gather_kernel<<<2048, 256, 0, stream>>>(B, rowst, csr, dinv, b2, Cb, N, sum2, sq2);
    prep_kernel<<<1, 128, 0, stream>>>(sum2, sq2, g2, be2, sc2, bi2, inv_n);

    // ---- out = bn0(x) + bn2(v2) ----
    final_kernel<<<1024, 256, 0, stream>>>(x, Cb, sc0, bi0, sc2, bi2, out, N);
}

// Round 3
// 448.387 us; speedup vs baseline: 5.5486x; 1.3080x over previous
//
#include <hip/hip_runtime.h>

#define CDIM 128
#define KPAD 136
#define EPS 1e-5f

typedef __attribute__((ext_vector_type(8))) short short8;
typedef __attribute__((ext_vector_type(4))) float f32x4;

__device__ __forceinline__ float bf2f(unsigned short u) {
    union { unsigned int i; float f; } v; v.i = ((unsigned int)u) << 16; return v.f;
}
__device__ __forceinline__ unsigned short f2bf(float f) {
    union { float f; unsigned int i; } v; v.f = f;
    unsigned int u = v.i;
    return (unsigned short)((u + 0x7FFFu + ((u >> 16) & 1u)) >> 16);  // RNE
}

// ---------------- int degree histogram ----------------
__global__ __launch_bounds__(256) void hist_kernel(const int* __restrict__ dst,
                                                   int* __restrict__ deg, int E) {
    int e = blockIdx.x * 256 + threadIdx.x;
    if (e < E) atomicAdd(&deg[dst[e]], 1);
}

__global__ __launch_bounds__(256) void dinv_kernel(const int* __restrict__ deg,
                                                   float* __restrict__ dinv, int N) {
    int i = blockIdx.x * 256 + threadIdx.x;
    if (i < N) dinv[i] = rsqrtf((float)deg[i] + 1.0f);  // +1 self-loop
}

// ---------------- scan stage 1: per-1024-chunk sums ----------------
__global__ __launch_bounds__(256) void scan1_kernel(const int* __restrict__ deg,
                                                    int* __restrict__ part, int N) {
    int t = threadIdx.x;
    int base = blockIdx.x * 1024 + t * 4;
    int s = 0;
    if (base + 3 < N) {
        int4 v = *(const int4*)(deg + base);
        s = v.x + v.y + v.z + v.w;
    } else {
        for (int k = 0; k < 4; ++k) { int i = base + k; if (i < N) s += deg[i]; }
    }
    for (int off = 32; off; off >>= 1) s += __shfl_down(s, off, 64);
    __shared__ int sh[4];
    if ((t & 63) == 0) sh[t >> 6] = s;
    __syncthreads();
    if (t == 0) part[blockIdx.x] = sh[0] + sh[1] + sh[2] + sh[3];
}

// ---------------- scan stage 2: exclusive scan of <=256 partials ----------------
__global__ __launch_bounds__(256) void scan2_kernel(int* __restrict__ part, int P) {
    int t = threadIdx.x;
    __shared__ int sh[256];
    int v = (t < P) ? part[t] : 0;
    sh[t] = v;
    __syncthreads();
    for (int off = 1; off < 256; off <<= 1) {
        int u = (t >= off) ? sh[t - off] : 0;
        __syncthreads();
        sh[t] += u;
        __syncthreads();
    }
    if (t < P) part[t] = sh[t] - v;  // exclusive
}

// ---------------- scan stage 3: rowstart + cursor ----------------
__global__ __launch_bounds__(256) void scan3_kernel(const int* __restrict__ deg,
                                                    const int* __restrict__ part,
                                                    int* __restrict__ rowst,
                                                    int* __restrict__ cursor, int N) {
    int t = threadIdx.x, b = blockIdx.x;
    int base = b * 1024 + t * 4;
    int d0 = 0, d1 = 0, d2 = 0, d3 = 0;
    if (base + 3 < N) {
        int4 v = *(const int4*)(deg + base);
        d0 = v.x; d1 = v.y; d2 = v.z; d3 = v.w;
    } else {
        if (base < N)     d0 = deg[base];
        if (base + 1 < N) d1 = deg[base + 1];
        if (base + 2 < N) d2 = deg[base + 2];
        if (base + 3 < N) d3 = deg[base + 3];
    }
    int c0 = d0, c1 = c0 + d1, c2 = c1 + d2, c3 = c2 + d3;
    __shared__ int sh[256];
    sh[t] = c3;
    __syncthreads();
    for (int off = 1; off < 256; off <<= 1) {
        int u = (t >= off) ? sh[t - off] : 0;
        __syncthreads();
        sh[t] += u;
        __syncthreads();
    }
    int basev = part[b] + sh[t] - c3;
    int r0 = basev, r1 = basev + c0, r2 = basev + c1, r3 = basev + c2;
    if (base < N)     { rowst[base] = r0;     cursor[base] = r0;     if (base == N - 1)     rowst[N] = r0 + d0; }
    if (base + 1 < N) { rowst[base + 1] = r1; cursor[base + 1] = r1; if (base + 1 == N - 1) rowst[N] = r1 + d1; }
    if (base + 2 < N) { rowst[base + 2] = r2; cursor[base + 2] = r2; if (base + 2 == N - 1) rowst[N] = r2 + d2; }
    if (base + 3 < N) { rowst[base + 3] = r3; cursor[base + 3] = r3; if (base + 3 == N - 1) rowst[N] = r3 + d3; }
}

// ---------------- scatter src into CSR ----------------
__global__ __launch_bounds__(256) void scatter_kernel(const int* __restrict__ src,
                                                      const int* __restrict__ dst,
                                                      int* __restrict__ cursor,
                                                      int* __restrict__ csr, int E) {
    int e = blockIdx.x * 256 + threadIdx.x;
    if (e < E) {
        int d = dst[e];
        int pos = atomicAdd(&cursor[d], 1);
        csr[pos] = src[e];
    }
}

// ---------------- per-feature stats over node dim (fp32 input) ----------------
__global__ __launch_bounds__(256) void stats_kernel(const float* __restrict__ v, int N,
                                                    float* __restrict__ sum,
                                                    float* __restrict__ sq) {
    __shared__ float s_sum[CDIM];
    __shared__ float s_sq[CDIM];
    int t = threadIdx.x;
    if (t < CDIM) { s_sum[t] = 0.f; s_sq[t] = 0.f; }
    __syncthreads();
    int cg = t & 31, rg = t >> 5;
    int c0 = cg * 4;
    float a0=0,a1=0,a2=0,a3=0,q0=0,q1=0,q2=0,q3=0;
    for (long row = (long)blockIdx.x * 8 + rg; row < N; row += (long)gridDim.x * 8) {
        float4 x4 = *(const float4*)(v + row * CDIM + c0);
        a0 += x4.x; q0 = fmaf(x4.x, x4.x, q0);
        a1 += x4.y; q1 = fmaf(x4.y, x4.y, q1);
        a2 += x4.z; q2 = fmaf(x4.z, x4.z, q2);
        a3 += x4.w; q3 = fmaf(x4.w, x4.w, q3);
    }
    atomicAdd(&s_sum[c0+0], a0); atomicAdd(&s_sum[c0+1], a1);
    atomicAdd(&s_sum[c0+2], a2); atomicAdd(&s_sum[c0+3], a3);
    atomicAdd(&s_sq[c0+0], q0);  atomicAdd(&s_sq[c0+1], q1);
    atomicAdd(&s_sq[c0+2], q2);  atomicAdd(&s_sq[c0+3], q3);
    __syncthreads();
    if (t < CDIM) { atomicAdd(&sum[t], s_sum[t]); atomicAdd(&sq[t], s_sq[t]); }
}

// ---------------- BN params ----------------
__global__ void prep_kernel(const float* __restrict__ sum, const float* __restrict__ sq,
                            const float* __restrict__ gamma, const float* __restrict__ beta,
                            float* __restrict__ scale, float* __restrict__ bias, float inv_n) {
    int c = threadIdx.x;
    float m = sum[c] * inv_n;
    float var = fmaf(-m, m, sq[c] * inv_n);
    float r = rsqrtf(var + EPS);
    float g = gamma[c] * r;
    scale[c] = g;
    bias[c] = fmaf(-m, g, beta[c]);
}

// ---------------- W -> bf16 transposed: Wt[n][k] = bf16(W[k][n]) ----------------
__global__ __launch_bounds__(256) void wprep_kernel(const float* __restrict__ W,
                                                    unsigned short* __restrict__ Wt) {
    int t = blockIdx.x * 256 + threadIdx.x;  // 4096 threads
    int k = t >> 5, n0 = (t & 31) * 4;
    float4 w = *(const float4*)(W + k * CDIM + n0);
    Wt[(n0 + 0) * CDIM + k] = f2bf(w.x);
    Wt[(n0 + 1) * CDIM + k] = f2bf(w.y);
    Wt[(n0 + 2) * CDIM + k] = f2bf(w.z);
    Wt[(n0 + 3) * CDIM + k] = f2bf(w.w);
}

// ---------------- MFMA GEMM: Y = bf16( (scale*X+bias) @ W ), bf16 out ----------------
// A and B fragments use the SAME assumed k-slot mapping (k = ks*32 + (lane>>4)*8 + j),
// which makes the result invariant to the true HW slot<->k bijection (A/B symmetric).
// C/D layout: col = lane&15, row = (lane>>4)*4 + reg  [m89 HW-verified].
template<bool BF16_IN>
__global__ __launch_bounds__(256) void gemm_mfma_kernel(const void* __restrict__ Xv,
                                                        const unsigned short* __restrict__ Wt,
                                                        const float* __restrict__ scale,
                                                        const float* __restrict__ bias,
                                                        unsigned short* __restrict__ Y, int N) {
    __shared__ unsigned short As[64 * KPAD];
    __shared__ unsigned short Ws[CDIM * KPAD];
    int t = threadIdx.x;
    long row0 = (long)blockIdx.x * 64;

    // stage Wt -> Ws (16384 ushorts)
    #pragma unroll
    for (int p = 0; p < 16; ++p) {
        int idx = p * 256 + t;
        int n = idx >> 5, c4 = (idx & 31) * 4;
        ushort4 w = *(const ushort4*)(Wt + n * CDIM + c4);
        *(ushort4*)&Ws[n * KPAD + c4] = w;
    }
    // stage A rows: BN-apply + bf16 cvt
    #pragma unroll
    for (int p = 0; p < 8; ++p) {
        int idx = p * 256 + t;
        int r = idx >> 5, c4 = (idx & 31) * 4;
        long row = row0 + r;
        float4 v;
        if (row < N) {
            if (BF16_IN) {
                ushort4 u = *(const ushort4*)((const unsigned short*)Xv + row * CDIM + c4);
                v = make_float4(bf2f(u.x), bf2f(u.y), bf2f(u.z), bf2f(u.w));
            } else {
                v = *(const float4*)((const float*)Xv + row * CDIM + c4);
            }
        } else {
            v = make_float4(0.f, 0.f, 0.f, 0.f);
        }
        float4 sc = *(const float4*)(scale + c4);
        float4 bi = *(const float4*)(bias + c4);
        ushort4 o;
        o.x = f2bf(fmaf(v.x, sc.x, bi.x));
        o.y = f2bf(fmaf(v.y, sc.y, bi.y));
        o.z = f2bf(fmaf(v.z, sc.z, bi.z));
        o.w = f2bf(fmaf(v.w, sc.w, bi.w));
        *(ushort4*)&As[r * KPAD + c4] = o;
    }
    __syncthreads();

    int lane = t & 63, wv = t >> 6;
    int m = lane & 15, hi = lane >> 4;
    const unsigned short* arow = &As[(wv * 16 + m) * KPAD + hi * 8];
    short8 a0 = *(const short8*)(arow);
    short8 a1 = *(const short8*)(arow + 32);
    short8 a2 = *(const short8*)(arow + 64);
    short8 a3 = *(const short8*)(arow + 96);
    f32x4 acc[8];
    #pragma unroll
    for (int nt = 0; nt < 8; ++nt) {
        const unsigned short* brow = &Ws[(nt * 16 + m) * KPAD + hi * 8];
        short8 b0 = *(const short8*)(brow);
        short8 b1 = *(const short8*)(brow + 32);
        short8 b2 = *(const short8*)(brow + 64);
        short8 b3 = *(const short8*)(brow + 96);
        f32x4 c = {0.f, 0.f, 0.f, 0.f};
        c = __builtin_amdgcn_mfma_f32_16x16x32_bf16(a0, b0, c, 0, 0, 0);
        c = __builtin_amdgcn_mfma_f32_16x16x32_bf16(a1, b1, c, 0, 0, 0);
        c = __builtin_amdgcn_mfma_f32_16x16x32_bf16(a2, b2, c, 0, 0, 0);
        c = __builtin_amdgcn_mfma_f32_16x16x32_bf16(a3, b3, c, 0, 0, 0);
        acc[nt] = c;
    }
    __syncthreads();
    // repack C to LDS (reuse As as 64 x 128, pitch KPAD) for coalesced stores
    #pragma unroll
    for (int nt = 0; nt < 8; ++nt) {
        #pragma unroll
        for (int rg = 0; rg < 4; ++rg) {
            int rr = wv * 16 + hi * 4 + rg;
            As[rr * KPAD + nt * 16 + m] = f2bf(acc[nt][rg]);
        }
    }
    __syncthreads();
    #pragma unroll
    for (int p = 0; p < 8; ++p) {
        int idx = p * 256 + t;
        int r = idx >> 5, c4 = (idx & 31) * 4;
        long row = row0 + r;
        if (row < N) {
            ushort4 o = *(const ushort4*)&As[r * KPAD + c4];
            *(ushort4*)(Y + row * CDIM + c4) = o;
        }
    }
}

// ------ fused gather-agg + self-loop + bias + relu + BN stats (bf16 h/vout) ------
__global__ __launch_bounds__(256) void gather_kernel(const unsigned short* __restrict__ h,
                                                     const int* __restrict__ rowst,
                                                     const int* __restrict__ csr,
                                                     const float* __restrict__ dinv,
                                                     const float* __restrict__ bvec,
                                                     unsigned short* __restrict__ vout, int N,
                                                     float* __restrict__ sum,
                                                     float* __restrict__ sq) {
    __shared__ float s_sum[CDIM];
    __shared__ float s_sq[CDIM];
    int t = threadIdx.x;
    if (t < CDIM) { s_sum[t] = 0.f; s_sq[t] = 0.f; }
    __syncthreads();
    int grp = t >> 5, lane = t & 31;
    int c0 = lane * 4;
    float4 bb = *(const float4*)(bvec + c0);
    float a0=0,a1=0,a2=0,a3=0,q0=0,q1=0,q2=0,q3=0;
    for (int n = blockIdx.x * 8 + grp; n < N; n += gridDim.x * 8) {
        int r0 = rowst[n], r1 = rowst[n + 1];
        float dn = dinv[n];
        float d2 = dn * dn;
        ushort4 hn = *(const ushort4*)(h + (long)n * CDIM + c0);
        float x0 = bf2f(hn.x) * d2, x1 = bf2f(hn.y) * d2;
        float x2 = bf2f(hn.z) * d2, x3 = bf2f(hn.w) * d2;
        int j = r0;
        for (; j + 4 <= r1; j += 4) {
            int s0 = csr[j], s1 = csr[j+1], s2 = csr[j+2], s3 = csr[j+3];
            float w0 = dinv[s0] * dn, w1 = dinv[s1] * dn;
            float w2 = dinv[s2] * dn, w3 = dinv[s3] * dn;
            ushort4 u0 = *(const ushort4*)(h + (long)s0 * CDIM + c0);
            ushort4 u1 = *(const ushort4*)(h + (long)s1 * CDIM + c0);
            ushort4 u2 = *(const ushort4*)(h + (long)s2 * CDIM + c0);
            ushort4 u3 = *(const ushort4*)(h + (long)s3 * CDIM + c0);
            x0 = fmaf(bf2f(u0.x), w0, x0); x1 = fmaf(bf2f(u0.y), w0, x1);
            x2 = fmaf(bf2f(u0.z), w0, x2); x3 = fmaf(bf2f(u0.w), w0, x3);
            x0 = fmaf(bf2f(u1.x), w1, x0); x1 = fmaf(bf2f(u1.y), w1, x1);
            x2 = fmaf(bf2f(u1.z), w1, x2); x3 = fmaf(bf2f(u1.w), w1, x3);
            x0 = fmaf(bf2f(u2.x), w2, x0); x1 = fmaf(bf2f(u2.y), w2, x1);
            x2 = fmaf(bf2f(u2.z), w2, x2); x3 = fmaf(bf2f(u2.w), w2, x3);
            x0 = fmaf(bf2f(u3.x), w3, x0); x1 = fmaf(bf2f(u3.y), w3, x1);
            x2 = fmaf(bf2f(u3.z), w3, x2); x3 = fmaf(bf2f(u3.w), w3, x3);
        }
        for (; j < r1; ++j) {
            int s0 = csr[j];
            float w0 = dinv[s0] * dn;
            ushort4 u0 = *(const ushort4*)(h + (long)s0 * CDIM + c0);
            x0 = fmaf(bf2f(u0.x), w0, x0); x1 = fmaf(bf2f(u0.y), w0, x1);
            x2 = fmaf(bf2f(u0.z), w0, x2); x3 = fmaf(bf2f(u0.w), w0, x3);
        }
        float o0 = fmaxf(x0 + bb.x, 0.f);
        float o1 = fmaxf(x1 + bb.y, 0.f);
        float o2 = fmaxf(x2 + bb.z, 0.f);
        float o3 = fmaxf(x3 + bb.w, 0.f);
        ushort4 ov;
        ov.x = f2bf(o0); ov.y = f2bf(o1); ov.z = f2bf(o2); ov.w = f2bf(o3);
        *(ushort4*)(vout + (long)n * CDIM + c0) = ov;
        a0 += o0; q0 = fmaf(o0, o0, q0);
        a1 += o1; q1 = fmaf(o1, o1, q1);
        a2 += o2; q2 = fmaf(o2, o2, q2);
        a3 += o3; q3 = fmaf(o3, o3, q3);
    }
    atomicAdd(&s_sum[c0+0], a0); atomicAdd(&s_sum[c0+1], a1);
    atomicAdd(&s_sum[c0+2], a2); atomicAdd(&s_sum[c0+3], a3);
    atomicAdd(&s_sq[c0+0], q0);  atomicAdd(&s_sq[c0+1], q1);
    atomicAdd(&s_sq[c0+2], q2);  atomicAdd(&s_sq[c0+3], q3);
    __syncthreads();
    if (t < CDIM) { atomicAdd(&sum[t], s_sum[t]); atomicAdd(&sq[t], s_sq[t]); }
}

// ---------------- final: out = bn0(x) + bn2(v2), v2 bf16 ----------------
__global__ __launch_bounds__(256) void final_kernel(const float* __restrict__ x,
                                                    const unsigned short* __restrict__ v,
                                                    const float* __restrict__ sc0,
                                                    const float* __restrict__ bi0,
                                                    const float* __restrict__ sc2,
                                                    const float* __restrict__ bi2,
                                                    float* __restrict__ out, int N) {
    int t = threadIdx.x;
    int cg = t & 31, rg = t >> 5;
    int c0 = cg * 4;
    float4 s0 = *(const float4*)(sc0 + c0);
    float4 b0 = *(const float4*)(bi0 + c0);
    float4 s2 = *(const float4*)(sc2 + c0);
    float4 b2 = *(const float4*)(bi2 + c0);
    for (long row = (long)blockIdx.x * 8 + rg; row < N; row += (long)gridDim.x * 8) {
        float4 xv = *(const float4*)(x + row * CDIM + c0);
        ushort4 vv = *(const ushort4*)(v + row * CDIM + c0);
        float4 o;
        o.x = fmaf(xv.x, s0.x, b0.x) + fmaf(bf2f(vv.x), s2.x, b2.x);
        o.y = fmaf(xv.y, s0.y, b0.y) + fmaf(bf2f(vv.y), s2.y, b2.y);
        o.z = fmaf(xv.z, s0.z, b0.z) + fmaf(bf2f(vv.z), s2.z, b2.z);
        o.w = fmaf(xv.w, s0.w, b0.w) + fmaf(bf2f(vv.w), s2.w, b2.w);
        *(float4*)(out + row * CDIM + c0) = o;
    }
}

extern "C" void kernel_launch(void* const* d_in, const int* in_sizes, int n_in,
                              void* d_out, int out_size, void* d_ws, size_t ws_size,
                              hipStream_t stream) {
    const float* x   = (const float*)d_in[0];
    const int*   ei  = (const int*)d_in[1];
    const float* g0  = (const float*)d_in[2];
    const float* be0 = (const float*)d_in[3];
    const float* W1  = (const float*)d_in[4];
    const float* b1  = (const float*)d_in[5];
    const float* g1  = (const float*)d_in[6];
    const float* be1 = (const float*)d_in[7];
    const float* W2  = (const float*)d_in[8];
    const float* b2  = (const float*)d_in[9];
    const float* g2  = (const float*)d_in[10];
    const float* be2 = (const float*)d_in[11];
    float* out = (float*)d_out;

    int N = in_sizes[0] / CDIM;
    int E = in_sizes[1] / 2;
    const int* src = ei;
    const int* dst = ei + E;

    size_t NC = (size_t)N * CDIM;
    unsigned short* Bb = (unsigned short*)d_ws;   // [N,128] bf16 h buffer
    unsigned short* Cb = Bb + NC;                 // [N,128] bf16 v buffer
    float* dinv = (float*)(Cb + NC);              // N
    float* stat = dinv + N;                       // 768 (zeroed)
    int*   deg  = (int*)(stat + 768);             // N (zeroed, contiguous with stat)
    int*   rowst= deg + N;                        // N+1 (padded to N+4)
    int*   cursor = rowst + N + 4;                // N
    int*   csr  = cursor + N;                     // E (rounded up to mult of 4)
    int*   part = csr + ((E + 3) & ~3);           // 256
    float* sb   = (float*)(part + 256);           // 768
    unsigned short* wt1 = (unsigned short*)(sb + 768);  // 16384
    unsigned short* wt2 = wt1 + CDIM * CDIM;            // 16384

    float* sum0 = stat;       float* sq0 = stat + 128;
    float* sum1 = stat + 256; float* sq1 = stat + 384;
    float* sum2 = stat + 512; float* sq2 = stat + 640;
    float* sc0 = sb;          float* bi0 = sb + 128;
    float* sc1 = sb + 256;    float* bi1 = sb + 384;
    float* sc2 = sb + 512;    float* bi2 = sb + 640;

    float inv_n = 1.0f / (float)N;
    int P = (N + 1023) / 1024;

    // zero stats + degree (contiguous region)
    hipMemsetAsync(stat, 0, (768 + (size_t)N) * sizeof(float), stream);

    // ---- CSR build (shared by both layers) ----
    hist_kernel<<<(E + 255) / 256, 256, 0, stream>>>(dst, deg, E);
    scan1_kernel<<<P, 256, 0, stream>>>(deg, part, N);
    scan2_kernel<<<1, 256, 0, stream>>>(part, P);
    scan3_kernel<<<P, 256, 0, stream>>>(deg, part, rowst, cursor, N);
    dinv_kernel<<<(N + 255) / 256, 256, 0, stream>>>(deg, dinv, N);
    scatter_kernel<<<(E + 255) / 256, 256, 0, stream>>>(src, dst, cursor, csr, E);

    // ---- weight prep (bf16, transposed) ----
    wprep_kernel<<<16, 256, 0, stream>>>(W1, wt1);
    wprep_kernel<<<16, 256, 0, stream>>>(W2, wt2);

    // ---- bn0 stats ----
    stats_kernel<<<1024, 256, 0, stream>>>(x, N, sum0, sq0);
    prep_kernel<<<1, 128, 0, stream>>>(sum0, sq0, g0, be0, sc0, bi0, inv_n);

    // ---- layer 1 ----
    gemm_mfma_kernel<false><<<(N + 63) / 64, 256, 0, stream>>>(x, wt1, sc0, bi0, Bb, N);
    gather_kernel<<<2048, 256, 0, stream>>>(Bb, rowst, csr, dinv, b1, Cb, N, sum1, sq1);
    prep_kernel<<<1, 128, 0, stream>>>(sum1, sq1, g1, be1, sc1, bi1, inv_n);

    // ---- layer 2 ----
    gemm_mfma_kernel<true><<<(N + 63) / 64, 256, 0, stream>>>(Cb, wt2, sc1, bi1, Bb, N);
    gather_kernel<<<2048, 256, 0, stream>>>(Bb, rowst, csr, dinv, b2, Cb, N, sum2, sq2);
    prep_kernel<<<1, 128, 0, stream>>>(sum2, sq2, g2, be2, sc2, bi2, inv_n);

    // ---- out = bn0(x) + bn2(v2) ----
    final_kernel<<<1024, 256, 0, stream>>>(x, Cb, sc0, bi0, sc2, bi2, out, N);
}